// Round 1
// baseline (860.854 us; speedup 1.0000x reference)
//
#include <hip/hip_runtime.h>
#include <hip/hip_bf16.h>

typedef __bf16 bf16x8 __attribute__((ext_vector_type(8)));
typedef float f32x4 __attribute__((ext_vector_type(4)));

// ---------------------------------------------------------------------------
// fp32 -> bf16 convert (for weight matrices)
// ---------------------------------------------------------------------------
__global__ __launch_bounds__(256) void cvt_bf16_kernel(const float* __restrict__ src,
                                                       __bf16* __restrict__ dst, int n) {
  int i = blockIdx.x * 256 + threadIdx.x;
  if (i < n) dst[i] = (__bf16)src[i];
}

// ---------------------------------------------------------------------------
// GroupNorm over [b, c, h*w], 32 groups of 16 channels; writes hnT[b, n, c] bf16
// One block per (b, g): stats over 16*4096 = 65536 contiguous floats.
// ---------------------------------------------------------------------------
__global__ __launch_bounds__(256) void groupnorm_kernel(
    const float* __restrict__ x, const float* __restrict__ gamma,
    const float* __restrict__ beta, __bf16* __restrict__ hnT) {
  const int N = 4096, C = 512, CPG = 16;
  const int b = blockIdx.x >> 5;
  const int g = blockIdx.x & 31;
  const int c0 = g * CPG;
  const int tid = threadIdx.x;
  const float* xb = x + ((size_t)b * C + c0) * N;  // contiguous 65536 floats

  float s1 = 0.f, s2 = 0.f;
  const float4* x4 = (const float4*)xb;
  for (int i = tid; i < CPG * N / 4; i += 256) {
    float4 t = x4[i];
    s1 += t.x + t.y + t.z + t.w;
    s2 += t.x * t.x + t.y * t.y + t.z * t.z + t.w * t.w;
  }
#pragma unroll
  for (int off = 32; off; off >>= 1) {
    s1 += __shfl_xor(s1, off);
    s2 += __shfl_xor(s2, off);
  }
  __shared__ float red1[4], red2[4];
  if ((tid & 63) == 0) { red1[tid >> 6] = s1; red2[tid >> 6] = s2; }
  __syncthreads();
  const float ts1 = red1[0] + red1[1] + red1[2] + red1[3];
  const float ts2 = red2[0] + red2[1] + red2[2] + red2[3];
  const float mean = ts1 * (1.f / 65536.f);
  const float var = ts2 * (1.f / 65536.f) - mean * mean;
  const float inv = rsqrtf(var + 1e-6f);

  const int cl = tid & 15;
  const float gm = gamma[c0 + cl] * inv;
  const float bt = beta[c0 + cl] - mean * gm;  // val = x*gm + bt

  __shared__ float tile[16][257];
  __bf16* hb = hnT + (size_t)b * N * C + c0;
  for (int nc = 0; nc < 16; ++nc) {
    __syncthreads();
#pragma unroll
    for (int r = 0; r < 16; ++r)
      tile[r][tid] = xb[r * N + nc * 256 + tid];
    __syncthreads();
#pragma unroll
    for (int w2 = 0; w2 < 16; ++w2) {
      int nl = w2 * 16 + (tid >> 4);
      float val = tile[cl][nl] * gm + bt;
      hb[(size_t)(nc * 256 + nl) * C + cl] = (__bf16)val;
    }
  }
}

// ---------------------------------------------------------------------------
// Row softmax over S[4096, 4096] fp32, in-place bf16 result at row stride 8192
// (bf16 row occupies the first half of each fp32 row's bytes).
// One block (256 thr) per row; entire row held in registers before writes.
// ---------------------------------------------------------------------------
__global__ __launch_bounds__(256) void softmax_kernel(float* __restrict__ S) {
  const int N = 4096;
  float* rp = S + (size_t)blockIdx.x * N;
  const int tid = threadIdx.x;
  float v[16];
  float mx = -1e30f;
#pragma unroll
  for (int i = 0; i < 16; ++i) {
    v[i] = rp[tid + i * 256];
    mx = fmaxf(mx, v[i]);
  }
#pragma unroll
  for (int off = 32; off; off >>= 1) mx = fmaxf(mx, __shfl_xor(mx, off));
  __shared__ float redm[4];
  if ((tid & 63) == 0) redm[tid >> 6] = mx;
  __syncthreads();
  mx = fmaxf(fmaxf(redm[0], redm[1]), fmaxf(redm[2], redm[3]));

  float sum = 0.f;
#pragma unroll
  for (int i = 0; i < 16; ++i) {
    v[i] = __expf(v[i] - mx);
    sum += v[i];
  }
#pragma unroll
  for (int off = 32; off; off >>= 1) sum += __shfl_xor(sum, off);
  __shared__ float reds[4];
  if ((tid & 63) == 0) reds[tid >> 6] = sum;
  __syncthreads();
  sum = reds[0] + reds[1] + reds[2] + reds[3];
  const float invs = 1.0f / sum;

  __bf16* bp = (__bf16*)rp;  // in-place: all reads already in registers
#pragma unroll
  for (int i = 0; i < 16; ++i) bp[tid + i * 256] = (__bf16)(v[i] * invs);
}

// ---------------------------------------------------------------------------
// Generic MFMA GEMM:  D[m,n] = scale * sum_k A[m,k] * B[n,k]  (+ bias)
// A: [M, K] row-major (lda elems), B: [N, K] row-major (ldb elems) — both bf16,
// per-lane-contiguous fragment loads (no LDS).
// Block = 4 waves (2x2), wave tile = 16*MI x 16*NI, block tile = 32*MI x 32*NI.
// EPI: 0 = write bf16, 1 = write f32, 2 = write f32 * xmul (elementwise)
// BIAS: 0 = none, 1 = bias[col], 2 = bias[row]
// ---------------------------------------------------------------------------
template <int EPI, int BIAS, int MI, int NI>
__global__ __launch_bounds__(256) void gemm_kernel(
    const __bf16* __restrict__ A, int lda, long long sA,
    const __bf16* __restrict__ Bm, int ldb, long long sB,
    void* __restrict__ Out, int ldo, long long sO,
    const float* __restrict__ bias, const float* __restrict__ xmul,
    long long sX, float scale, int K) {
  const int z = blockIdx.z;
  const __bf16* Az = A + (size_t)z * sA;
  const __bf16* Bz = Bm + (size_t)z * sB;
  const int tid = threadIdx.x;
  const int lane = tid & 63;
  const int wid = tid >> 6;
  const int wr = wid >> 1, wc = wid & 1;
  const int wm = blockIdx.y * (32 * MI) + wr * (16 * MI);
  const int wn = blockIdx.x * (32 * NI) + wc * (16 * NI);
  const int lr = lane & 15;
  const int lk = (lane >> 4) * 8;

  const __bf16* pa[MI];
  const __bf16* pb[NI];
#pragma unroll
  for (int i = 0; i < MI; ++i) pa[i] = Az + (size_t)(wm + i * 16 + lr) * lda + lk;
#pragma unroll
  for (int j = 0; j < NI; ++j) pb[j] = Bz + (size_t)(wn + j * 16 + lr) * ldb + lk;

  f32x4 acc[MI][NI];
#pragma unroll
  for (int i = 0; i < MI; ++i)
#pragma unroll
    for (int j = 0; j < NI; ++j) acc[i][j] = f32x4{0.f, 0.f, 0.f, 0.f};

  for (int k = 0; k < K; k += 32) {
    bf16x8 a[MI], b[NI];
#pragma unroll
    for (int i = 0; i < MI; ++i) { a[i] = *(const bf16x8*)pa[i]; pa[i] += 32; }
#pragma unroll
    for (int j = 0; j < NI; ++j) { b[j] = *(const bf16x8*)pb[j]; pb[j] += 32; }
#pragma unroll
    for (int i = 0; i < MI; ++i)
#pragma unroll
      for (int j = 0; j < NI; ++j)
        acc[i][j] = __builtin_amdgcn_mfma_f32_16x16x32_bf16(a[i], b[j], acc[i][j], 0, 0, 0);
  }

  // Epilogue. D mapping (verified m89): col = lane&15, row = (lane>>4)*4 + reg.
#pragma unroll
  for (int i = 0; i < MI; ++i) {
#pragma unroll
    for (int r = 0; r < 4; ++r) {
      const int row = wm + i * 16 + (lane >> 4) * 4 + r;
#pragma unroll
      for (int j = 0; j < NI; ++j) {
        const int col = wn + j * 16 + lr;
        float val = acc[i][j][r] * scale;
        if (BIAS == 1) val += bias[col];
        if (BIAS == 2) val += bias[row];
        const size_t off = (size_t)z * sO + (size_t)row * ldo + col;
        if (EPI == 0) {
          ((__bf16*)Out)[off] = (__bf16)val;
        } else if (EPI == 1) {
          ((float*)Out)[off] = val;
        } else {
          ((float*)Out)[off] = xmul[(size_t)z * sX + (size_t)row * ldo + col] * val;
        }
      }
    }
  }
}

// ---------------------------------------------------------------------------
// Workspace layout (bytes):
//   hnT  [4,4096,512] bf16 @ 0        (16 MiB)
//   qT   [4,4096,512] bf16 @ 16 MiB   (16 MiB)
//   kT   [4,4096,512] bf16 @ 32 MiB   (16 MiB)
//   v    [4,512,4096] bf16 @ 48 MiB   (16 MiB)
//   a2T  [4,4096,512] bf16 @ 64 MiB   (16 MiB)
//   wq/wk/wv/wo bf16        @ 80 MiB  (2 MiB)
//   S    [4096,4096] f32    @ 82 MiB  (64 MiB)   -> total 146 MiB
// ---------------------------------------------------------------------------
extern "C" void kernel_launch(void* const* d_in, const int* in_sizes, int n_in,
                              void* d_out, int out_size, void* d_ws, size_t ws_size,
                              hipStream_t stream) {
  const int C = 512, N = 4096;
  const float* x = (const float*)d_in[0];
  const float* gng = (const float*)d_in[1];
  const float* gnb = (const float*)d_in[2];
  const float* wq = (const float*)d_in[3];
  const float* bq = (const float*)d_in[4];
  const float* wk = (const float*)d_in[5];
  const float* bk = (const float*)d_in[6];
  const float* wv = (const float*)d_in[7];
  const float* bv = (const float*)d_in[8];
  const float* wo = (const float*)d_in[9];
  const float* bo = (const float*)d_in[10];

  char* ws = (char*)d_ws;
  const size_t MB = 1ull << 20;
  __bf16* hnT = (__bf16*)(ws + 0);
  __bf16* qT  = (__bf16*)(ws + 16 * MB);
  __bf16* kT  = (__bf16*)(ws + 32 * MB);
  __bf16* v   = (__bf16*)(ws + 48 * MB);
  __bf16* a2T = (__bf16*)(ws + 64 * MB);
  __bf16* wqB = (__bf16*)(ws + 80 * MB);
  __bf16* wkB = (__bf16*)(ws + 80 * MB + 512 * 1024);
  __bf16* wvB = (__bf16*)(ws + 81 * MB);
  __bf16* woB = (__bf16*)(ws + 81 * MB + 512 * 1024);
  float* S    = (float*)(ws + 82 * MB);

  const long long NC = (long long)N * C;

  // weights -> bf16
  cvt_bf16_kernel<<<1024, 256, 0, stream>>>(wq, wqB, C * C);
  cvt_bf16_kernel<<<1024, 256, 0, stream>>>(wk, wkB, C * C);
  cvt_bf16_kernel<<<1024, 256, 0, stream>>>(wv, wvB, C * C);
  cvt_bf16_kernel<<<1024, 256, 0, stream>>>(wo, woB, C * C);

  // GroupNorm -> hnT [b, n, c] bf16
  groupnorm_kernel<<<128, 256, 0, stream>>>(x, gng, gnb, hnT);

  // qT[b,n,o] = sum_c hnT[b,n,c] * wq[o,c] + bq[o]
  gemm_kernel<0, 1, 4, 4><<<dim3(4, 32, 4), 256, 0, stream>>>(
      hnT, C, NC, wqB, C, 0, qT, C, NC, bq, nullptr, 0, 1.f, C);
  gemm_kernel<0, 1, 4, 4><<<dim3(4, 32, 4), 256, 0, stream>>>(
      hnT, C, NC, wkB, C, 0, kT, C, NC, bk, nullptr, 0, 1.f, C);
  // v[b,o,n] = sum_c wv[o,c] * hnT[b,n,c] + bv[o]
  gemm_kernel<0, 2, 4, 4><<<dim3(32, 4, 4), 256, 0, stream>>>(
      wvB, C, 0, hnT, C, NC, v, N, NC, bv, nullptr, 0, 1.f, C);

  const float scl = 0.044194173824159216f;  // 512^-0.5
  for (int b = 0; b < 4; ++b) {
    const __bf16* qb = qT + (size_t)b * NC;
    const __bf16* kb = kT + (size_t)b * NC;
    const __bf16* vb = v + (size_t)b * NC;
    __bf16* a2b = a2T + (size_t)b * NC;
    // S[i,j] = scl * sum_c qT[i,c] * kT[j,c]
    gemm_kernel<1, 0, 4, 4><<<dim3(32, 32, 1), 256, 0, stream>>>(
        qb, C, 0, kb, C, 0, S, N, 0, nullptr, nullptr, 0, scl, C);
    // row softmax, in-place bf16 (row stride 2N bf16 elems)
    softmax_kernel<<<4096, 256, 0, stream>>>(S);
    // a2T[i,c] = sum_j P[i,j] * v[c,j]
    gemm_kernel<0, 0, 4, 2><<<dim3(8, 32, 1), 256, 0, stream>>>(
        (const __bf16*)S, 2 * N, 0, vb, N, 0, a2b, C, 0, nullptr, nullptr, 0, 1.f, N);
  }

  // out[b,o,n] = x[b,o,n] * (sum_c wo[o,c] * a2T[b,n,c] + bo[o])
  gemm_kernel<2, 2, 4, 4><<<dim3(32, 4, 4), 256, 0, stream>>>(
      woB, C, 0, a2T, C, NC, d_out, N, NC, bo, x, NC, 1.f, C);
}

// Round 2
// 370.758 us; speedup vs baseline: 2.3219x; 2.3219x over previous
//
#include <hip/hip_runtime.h>
#include <hip/hip_bf16.h>
#include <stdint.h>

typedef __bf16 bf16x8 __attribute__((ext_vector_type(8)));
typedef float f32x4 __attribute__((ext_vector_type(4)));

__device__ __forceinline__ void gload_lds16(const __bf16* g, __bf16* l) {
  __builtin_amdgcn_global_load_lds(
      (const __attribute__((address_space(1))) void*)g,
      (__attribute__((address_space(3))) void*)l, 16, 0, 0);
}

// ---------------------------------------------------------------------------
// fp32 -> bf16 convert for the 4 weight matrices (one launch)
// ---------------------------------------------------------------------------
__global__ __launch_bounds__(256) void cvt4_kernel(const float* __restrict__ s0,
                                                   const float* __restrict__ s1,
                                                   const float* __restrict__ s2,
                                                   const float* __restrict__ s3,
                                                   __bf16* __restrict__ dst) {
  int i = blockIdx.x * 256 + threadIdx.x;  // 4 * 512 * 512 = 1048576 total
  const float* srcs[4] = {s0, s1, s2, s3};
  int m = i >> 18;
  dst[i] = (__bf16)srcs[m][i & 262143];
}

// ---------------------------------------------------------------------------
// GroupNorm over [b, c, h*w], 32 groups of 16 channels; writes hnT[b, n, c] bf16
// One block per (b, g): stats over 16*4096 = 65536 contiguous floats.
// ---------------------------------------------------------------------------
__global__ __launch_bounds__(256) void groupnorm_kernel(
    const float* __restrict__ x, const float* __restrict__ gamma,
    const float* __restrict__ beta, __bf16* __restrict__ hnT) {
  const int N = 4096, C = 512, CPG = 16;
  const int b = blockIdx.x >> 5;
  const int g = blockIdx.x & 31;
  const int c0 = g * CPG;
  const int tid = threadIdx.x;
  const float* xb = x + ((size_t)b * C + c0) * N;

  float s1 = 0.f, s2 = 0.f;
  const float4* x4 = (const float4*)xb;
  for (int i = tid; i < CPG * N / 4; i += 256) {
    float4 t = x4[i];
    s1 += t.x + t.y + t.z + t.w;
    s2 += t.x * t.x + t.y * t.y + t.z * t.z + t.w * t.w;
  }
#pragma unroll
  for (int off = 32; off; off >>= 1) {
    s1 += __shfl_xor(s1, off);
    s2 += __shfl_xor(s2, off);
  }
  __shared__ float red1[4], red2[4];
  if ((tid & 63) == 0) { red1[tid >> 6] = s1; red2[tid >> 6] = s2; }
  __syncthreads();
  const float ts1 = red1[0] + red1[1] + red1[2] + red1[3];
  const float ts2 = red2[0] + red2[1] + red2[2] + red2[3];
  const float mean = ts1 * (1.f / 65536.f);
  const float var = ts2 * (1.f / 65536.f) - mean * mean;
  const float inv = rsqrtf(var + 1e-6f);

  const int cl = tid & 15;
  const float gm = gamma[c0 + cl] * inv;
  const float bt = beta[c0 + cl] - mean * gm;

  __shared__ float tile[16][257];
  __bf16* hb = hnT + (size_t)b * N * C + c0;
  for (int nc = 0; nc < 16; ++nc) {
    __syncthreads();
#pragma unroll
    for (int r = 0; r < 16; ++r)
      tile[r][tid] = xb[r * N + nc * 256 + tid];
    __syncthreads();
#pragma unroll
    for (int w2 = 0; w2 < 16; ++w2) {
      int nl = w2 * 16 + (tid >> 4);
      float val = tile[cl][nl] * gm + bt;
      hb[(size_t)(nc * 256 + nl) * C + cl] = (__bf16)val;
    }
  }
}

// ---------------------------------------------------------------------------
// Row softmax over bf16 rows of length 4096, in place. One block per row.
// ---------------------------------------------------------------------------
__global__ __launch_bounds__(256) void softmax_bf16_kernel(__bf16* __restrict__ S) {
  const int N = 4096;
  __bf16* rp = S + (size_t)blockIdx.x * N;
  const int tid = threadIdx.x;
  bf16x8 v0 = ((const bf16x8*)rp)[tid * 2];
  bf16x8 v1 = ((const bf16x8*)rp)[tid * 2 + 1];
  float f[16];
#pragma unroll
  for (int i = 0; i < 8; ++i) { f[i] = (float)v0[i]; f[8 + i] = (float)v1[i]; }

  float mx = -1e30f;
#pragma unroll
  for (int i = 0; i < 16; ++i) mx = fmaxf(mx, f[i]);
#pragma unroll
  for (int off = 32; off; off >>= 1) mx = fmaxf(mx, __shfl_xor(mx, off));
  __shared__ float redm[4];
  if ((tid & 63) == 0) redm[tid >> 6] = mx;
  __syncthreads();
  mx = fmaxf(fmaxf(redm[0], redm[1]), fmaxf(redm[2], redm[3]));

  float sum = 0.f;
#pragma unroll
  for (int i = 0; i < 16; ++i) {
    f[i] = __expf(f[i] - mx);
    sum += f[i];
  }
#pragma unroll
  for (int off = 32; off; off >>= 1) sum += __shfl_xor(sum, off);
  __shared__ float reds[4];
  if ((tid & 63) == 0) reds[tid >> 6] = sum;
  __syncthreads();
  sum = reds[0] + reds[1] + reds[2] + reds[3];
  const float invs = 1.0f / sum;

  bf16x8 o0, o1;
#pragma unroll
  for (int i = 0; i < 8; ++i) {
    o0[i] = (__bf16)(f[i] * invs);
    o1[i] = (__bf16)(f[8 + i] * invs);
  }
  ((bf16x8*)rp)[tid * 2] = o0;
  ((bf16x8*)rp)[tid * 2 + 1] = o1;
}

// ---------------------------------------------------------------------------
// m97-structure MFMA GEMM: D[m,n] = scale * sum_k A[m,k] * B[n,k] (+ bias)
// A: [M,K] (lda), B: [N,K] (ldb), bf16. Block tile 128x128, BK=32, 4 waves 2x2.
// Staging: global_load_lds width 16, linear LDS [128][32]; chunk = 1024B,
// wave w owns chunks {2w, 2w+1}: lane l -> row c*16 + (l>>2), col (l&3)*8.
// EPI: 0 = bf16 out, 1 = f32 out, 2 = f32 out * xmul. BIAS: 0 none, 1 col, 2 row.
// Requires M%128==0, N%128==0, K%32==0.
// ---------------------------------------------------------------------------
template <int EPI, int BIAS>
__global__ __launch_bounds__(256) void gemm_lds_kernel(
    const __bf16* __restrict__ A, int lda, long long sA,
    const __bf16* __restrict__ Bm, int ldb, long long sB,
    void* __restrict__ Out, int ldo, long long sO,
    const float* __restrict__ bias, const float* __restrict__ xmul,
    long long sX, float scale, int K) {
  __shared__ __bf16 sTa[128 * 32];
  __shared__ __bf16 sTb[128 * 32];
  const int z = blockIdx.z;
  const int tid = threadIdx.x;
  const int lane = tid & 63;
  const int wid = tid >> 6;
  const int wr = wid >> 1, wc = wid & 1;
  const int tm0 = blockIdx.y * 128, tn0 = blockIdx.x * 128;
  const int lr = lane & 15, lk = (lane >> 4) * 8;

  // staging pointers
  const int ch0 = wid * 2;
  const int srow = lane >> 2;
  const int scol = (lane & 3) * 8;
  const __bf16* gA0 = A + (size_t)z * sA + (size_t)(tm0 + ch0 * 16 + srow) * lda + scol;
  const __bf16* gA1 = gA0 + (size_t)16 * lda;
  const __bf16* gB0 = Bm + (size_t)z * sB + (size_t)(tn0 + ch0 * 16 + srow) * ldb + scol;
  const __bf16* gB1 = gB0 + (size_t)16 * ldb;
  __bf16* lA0 = sTa + ch0 * 512;
  __bf16* lA1 = lA0 + 512;
  __bf16* lB0 = sTb + ch0 * 512;
  __bf16* lB1 = lB0 + 512;

  // fragment read pointers (row stride 32 elems = 64 B)
  const __bf16* fa = sTa + (wr * 64 + lr) * 32 + lk;
  const __bf16* fb = sTb + (wc * 64 + lr) * 32 + lk;

  f32x4 acc[4][4];
#pragma unroll
  for (int i = 0; i < 4; ++i)
#pragma unroll
    for (int j = 0; j < 4; ++j) acc[i][j] = f32x4{0.f, 0.f, 0.f, 0.f};

  for (int k = 0; k < K; k += 32) {
    if (k) __syncthreads();  // previous iteration's ds_reads done before overwrite
    gload_lds16(gA0, lA0);
    gload_lds16(gA1, lA1);
    gload_lds16(gB0, lB0);
    gload_lds16(gB1, lB1);
    gA0 += 32; gA1 += 32; gB0 += 32; gB1 += 32;
    __syncthreads();  // compiler drains vmcnt(0) before s_barrier -> LDS valid

    bf16x8 a[4], b[4];
#pragma unroll
    for (int i = 0; i < 4; ++i) a[i] = *(const bf16x8*)(fa + i * 512);
#pragma unroll
    for (int j = 0; j < 4; ++j) b[j] = *(const bf16x8*)(fb + j * 512);
#pragma unroll
    for (int i = 0; i < 4; ++i)
#pragma unroll
      for (int j = 0; j < 4; ++j)
        acc[i][j] = __builtin_amdgcn_mfma_f32_16x16x32_bf16(a[i], b[j], acc[i][j], 0, 0, 0);
  }

  // Epilogue. D mapping (verified m89): col = lane&15, row = (lane>>4)*4 + reg.
  const int wm = tm0 + wr * 64, wn = tn0 + wc * 64;
#pragma unroll
  for (int i = 0; i < 4; ++i) {
#pragma unroll
    for (int r = 0; r < 4; ++r) {
      const int row = wm + i * 16 + (lane >> 4) * 4 + r;
#pragma unroll
      for (int j = 0; j < 4; ++j) {
        const int col = wn + j * 16 + lr;
        float val = acc[i][j][r] * scale;
        if (BIAS == 1) val += bias[col];
        if (BIAS == 2) val += bias[row];
        const size_t off = (size_t)z * sO + (size_t)row * ldo + col;
        if (EPI == 0) {
          ((__bf16*)Out)[off] = (__bf16)val;
        } else if (EPI == 1) {
          ((float*)Out)[off] = val;
        } else {
          ((float*)Out)[off] = xmul[(size_t)z * sX + (size_t)row * ldo + col] * val;
        }
      }
    }
  }
}

// ---------------------------------------------------------------------------
// Workspace (batched path, 210 MiB):
//   hnT [4,4096,512] bf16 @ 0      qT @ 16MB    kT @ 32MB
//   v   [4,512,4096] bf16 @ 48MB   a2T @ 64MB   weights bf16 @ 80MB (2MB)
//   S4  [4,4096,4096] bf16 @ 82MB (128MB)
// Serial fallback uses only S4[0] (32 MB) -> 114 MiB.
// ---------------------------------------------------------------------------
extern "C" void kernel_launch(void* const* d_in, const int* in_sizes, int n_in,
                              void* d_out, int out_size, void* d_ws, size_t ws_size,
                              hipStream_t stream) {
  const int C = 512, N = 4096;
  const float* x = (const float*)d_in[0];
  const float* gng = (const float*)d_in[1];
  const float* gnb = (const float*)d_in[2];
  const float* wq = (const float*)d_in[3];
  const float* bq = (const float*)d_in[4];
  const float* wk = (const float*)d_in[5];
  const float* bk = (const float*)d_in[6];
  const float* wv = (const float*)d_in[7];
  const float* bv = (const float*)d_in[8];
  const float* wo = (const float*)d_in[9];
  const float* bo = (const float*)d_in[10];

  char* ws = (char*)d_ws;
  const size_t MB = 1ull << 20;
  __bf16* hnT = (__bf16*)(ws + 0);
  __bf16* qT  = (__bf16*)(ws + 16 * MB);
  __bf16* kT  = (__bf16*)(ws + 32 * MB);
  __bf16* v   = (__bf16*)(ws + 48 * MB);
  __bf16* a2T = (__bf16*)(ws + 64 * MB);
  __bf16* wqB = (__bf16*)(ws + 80 * MB);
  __bf16* wkB = wqB + 262144;
  __bf16* wvB = wkB + 262144;
  __bf16* woB = wvB + 262144;
  __bf16* S4  = (__bf16*)(ws + 82 * MB);

  const long long NC = (long long)N * C;
  const long long NN = (long long)N * N;
  const float scl = 0.044194173824159216f;  // 512^-0.5
  const bool batched = ws_size >= 82 * MB + (size_t)4 * NN * 2;

  cvt4_kernel<<<4096, 256, 0, stream>>>(wq, wk, wv, wo, wqB);
  groupnorm_kernel<<<128, 256, 0, stream>>>(x, gng, gnb, hnT);

  // qT[b,n,o] / kT[b,n,o]
  gemm_lds_kernel<0, 1><<<dim3(4, 32, 4), 256, 0, stream>>>(
      hnT, C, NC, wqB, C, 0, qT, C, NC, bq, nullptr, 0, 1.f, C);
  gemm_lds_kernel<0, 1><<<dim3(4, 32, 4), 256, 0, stream>>>(
      hnT, C, NC, wkB, C, 0, kT, C, NC, bk, nullptr, 0, 1.f, C);
  // v[b,o,n]
  gemm_lds_kernel<0, 2><<<dim3(32, 4, 4), 256, 0, stream>>>(
      wvB, C, 0, hnT, C, NC, v, N, NC, bv, nullptr, 0, 1.f, C);

  if (batched) {
    // S4[b,i,j] = scl * q_i . k_j   (bf16)
    gemm_lds_kernel<0, 0><<<dim3(32, 32, 4), 256, 0, stream>>>(
        qT, C, NC, kT, C, NC, S4, N, NN, nullptr, nullptr, 0, scl, C);
    softmax_bf16_kernel<<<4 * 4096, 256, 0, stream>>>(S4);
    // a2T[b,i,c] = sum_j P[i,j] v[c,j]
    gemm_lds_kernel<0, 0><<<dim3(4, 32, 4), 256, 0, stream>>>(
        S4, N, NN, v, N, NC, a2T, C, NC, nullptr, nullptr, 0, 1.f, N);
  } else {
    for (int b = 0; b < 4; ++b) {
      gemm_lds_kernel<0, 0><<<dim3(32, 32, 1), 256, 0, stream>>>(
          qT + (size_t)b * NC, C, 0, kT + (size_t)b * NC, C, 0, S4, N, 0,
          nullptr, nullptr, 0, scl, C);
      softmax_bf16_kernel<<<4096, 256, 0, stream>>>(S4);
      gemm_lds_kernel<0, 0><<<dim3(4, 32, 1), 256, 0, stream>>>(
          S4, N, 0, v + (size_t)b * NC, N, 0, a2T + (size_t)b * NC, C, 0,
          nullptr, nullptr, 0, 1.f, N);
    }
  }

  // out[b,o,n] = x[b,o,n] * (sum_c wo[o,c] * a2T[b,n,c] + bo[o])
  gemm_lds_kernel<2, 2><<<dim3(32, 4, 4), 256, 0, stream>>>(
      woB, C, 0, a2T, C, NC, d_out, N, NC, bo, x, NC, 1.f, C);
}

// Round 3
// 322.475 us; speedup vs baseline: 2.6695x; 1.1497x over previous
//
#include <hip/hip_runtime.h>
#include <hip/hip_bf16.h>
#include <stdint.h>

typedef __bf16 bf16x8 __attribute__((ext_vector_type(8)));
typedef __bf16 bf16x4 __attribute__((ext_vector_type(4)));
typedef float f32x4 __attribute__((ext_vector_type(4)));

__device__ __forceinline__ void gload_lds16(const __bf16* g, __bf16* l) {
  __builtin_amdgcn_global_load_lds(
      (const __attribute__((address_space(1))) void*)g,
      (__attribute__((address_space(3))) void*)l, 16, 0, 0);
}

// ---------------------------------------------------------------------------
// fp32 -> bf16 convert for the 4 weight matrices (contiguous dst)
// ---------------------------------------------------------------------------
__global__ __launch_bounds__(256) void cvt4_kernel(const float* __restrict__ s0,
                                                   const float* __restrict__ s1,
                                                   const float* __restrict__ s2,
                                                   const float* __restrict__ s3,
                                                   __bf16* __restrict__ dst) {
  int i = blockIdx.x * 256 + threadIdx.x;  // 4 * 512 * 512 = 1048576 total
  const float* srcs[4] = {s0, s1, s2, s3};
  int m = i >> 18;
  dst[i] = (__bf16)srcs[m][i & 262143];
}

__global__ __launch_bounds__(256) void biascat_kernel(const float* __restrict__ bq,
                                                      const float* __restrict__ bk,
                                                      float* __restrict__ bqk) {
  int i = blockIdx.x * 256 + threadIdx.x;  // 1024
  bqk[i] = (i < 512) ? bq[i] : bk[i - 512];
}

// ---------------------------------------------------------------------------
// GN1a: stream x fp32 once; write xbf (bf16 copy) + per-(b,g,slice) partial sums.
// Grid: (b=4) x (g=32) x (s=8) = 1024 blocks; each handles 8192 contiguous floats.
// ---------------------------------------------------------------------------
__global__ __launch_bounds__(256) void gn1a_kernel(const float* __restrict__ x,
                                                   __bf16* __restrict__ xbf,
                                                   float2* __restrict__ part) {
  const int tid = threadIdx.x;
  const int s = blockIdx.x & 7;
  const int g = (blockIdx.x >> 3) & 31;
  const int b = blockIdx.x >> 8;
  const size_t base4 = (((size_t)b * 512 + g * 16) * 4096 + s * 8192) >> 2;  // float4 idx
  const float4* x4 = (const float4*)x;
  bf16x4* o4 = (bf16x4*)xbf;

  float s1 = 0.f, s2 = 0.f;
#pragma unroll
  for (int j = 0; j < 8; ++j) {
    float4 t = x4[base4 + tid + j * 256];
    s1 += t.x + t.y + t.z + t.w;
    s2 += t.x * t.x + t.y * t.y + t.z * t.z + t.w * t.w;
    bf16x4 o;
    o[0] = (__bf16)t.x; o[1] = (__bf16)t.y; o[2] = (__bf16)t.z; o[3] = (__bf16)t.w;
    o4[base4 + tid + j * 256] = o;
  }
#pragma unroll
  for (int off = 32; off; off >>= 1) {
    s1 += __shfl_xor(s1, off);
    s2 += __shfl_xor(s2, off);
  }
  __shared__ float r1[4], r2[4];
  if ((tid & 63) == 0) { r1[tid >> 6] = s1; r2[tid >> 6] = s2; }
  __syncthreads();
  if (tid == 0)
    part[blockIdx.x] = float2{r1[0] + r1[1] + r1[2] + r1[3],
                              r2[0] + r2[1] + r2[2] + r2[3]};
}

// ---------------------------------------------------------------------------
// GN1b: reduce partials -> per-channel (gm, bt). Grid: 4 blocks (b) x 512 thr.
// ---------------------------------------------------------------------------
__global__ __launch_bounds__(512) void gn1b_kernel(const float2* __restrict__ part,
                                                   const float* __restrict__ gamma,
                                                   const float* __restrict__ beta,
                                                   float2* __restrict__ gmbt) {
  const int b = blockIdx.x;
  const int t = threadIdx.x;
  __shared__ float sm[32], si[32];
  if (t < 32) {
    float s1 = 0.f, s2 = 0.f;
#pragma unroll
    for (int j = 0; j < 8; ++j) {
      float2 p = part[(b * 32 + t) * 8 + j];
      s1 += p.x; s2 += p.y;
    }
    const float mean = s1 * (1.f / 65536.f);
    const float var = s2 * (1.f / 65536.f) - mean * mean;
    sm[t] = mean;
    si[t] = rsqrtf(var + 1e-6f);
  }
  __syncthreads();
  const int g = t >> 4;
  const float gm = gamma[t] * si[g];
  gmbt[b * 512 + t] = float2{gm, beta[t] - sm[g] * gm};
}

// ---------------------------------------------------------------------------
// GN2: normalize + transpose. xbf [b,c,n] bf16 -> hnT [b,n,c] bf16.
// Grid (n-tiles=64, c-tiles=8, b=4), 64x64 tiles via LDS.
// ---------------------------------------------------------------------------
__global__ __launch_bounds__(256) void gn2_kernel(const __bf16* __restrict__ xbf,
                                                  const float2* __restrict__ gmbt,
                                                  __bf16* __restrict__ hnT) {
  const int b = blockIdx.z;
  const int c0 = blockIdx.y * 64;
  const int n0 = blockIdx.x * 64;
  const int t = threadIdx.x;
  __shared__ __bf16 tile[64][72];

  {
    const int row = t >> 2;             // c within tile
    const int col = (t & 3) * 16;       // n within tile
    const __bf16* src = xbf + ((size_t)(b * 512 + c0 + row)) * 4096 + n0 + col;
    bf16x8 u0 = *(const bf16x8*)src;
    bf16x8 u1 = *(const bf16x8*)(src + 8);
    *(bf16x8*)&tile[row][col] = u0;
    *(bf16x8*)&tile[row][col + 8] = u1;
  }
  __syncthreads();
  {
    const int nrow = t >> 2;            // n within tile
    const int cc = (t & 3) * 16;        // c within tile
    bf16x8 o0, o1;
#pragma unroll
    for (int j = 0; j < 16; ++j) {
      const int c = c0 + cc + j;
      float2 s = gmbt[b * 512 + c];
      float val = (float)tile[cc + j][nrow] * s.x + s.y;
      if (j < 8) o0[j] = (__bf16)val; else o1[j - 8] = (__bf16)val;
    }
    __bf16* dst = hnT + ((size_t)b * 4096 + n0 + nrow) * 512 + c0 + cc;
    *(bf16x8*)dst = o0;
    *(bf16x8*)(dst + 8) = o1;
  }
}

// ---------------------------------------------------------------------------
// Row softmax over bf16 rows of length 4096, in place. One block per row.
// ---------------------------------------------------------------------------
__global__ __launch_bounds__(256) void softmax_bf16_kernel(__bf16* __restrict__ S) {
  const int N = 4096;
  __bf16* rp = S + (size_t)blockIdx.x * N;
  const int tid = threadIdx.x;
  bf16x8 v0 = ((const bf16x8*)rp)[tid * 2];
  bf16x8 v1 = ((const bf16x8*)rp)[tid * 2 + 1];
  float f[16];
#pragma unroll
  for (int i = 0; i < 8; ++i) { f[i] = (float)v0[i]; f[8 + i] = (float)v1[i]; }

  float mx = -1e30f;
#pragma unroll
  for (int i = 0; i < 16; ++i) mx = fmaxf(mx, f[i]);
#pragma unroll
  for (int off = 32; off; off >>= 1) mx = fmaxf(mx, __shfl_xor(mx, off));
  __shared__ float redm[4];
  if ((tid & 63) == 0) redm[tid >> 6] = mx;
  __syncthreads();
  mx = fmaxf(fmaxf(redm[0], redm[1]), fmaxf(redm[2], redm[3]));

  float sum = 0.f;
#pragma unroll
  for (int i = 0; i < 16; ++i) {
    f[i] = __expf(f[i] - mx);
    sum += f[i];
  }
#pragma unroll
  for (int off = 32; off; off >>= 1) sum += __shfl_xor(sum, off);
  __shared__ float reds[4];
  if ((tid & 63) == 0) reds[tid >> 6] = sum;
  __syncthreads();
  sum = reds[0] + reds[1] + reds[2] + reds[3];
  const float invs = 1.0f / sum;

  bf16x8 o0, o1;
#pragma unroll
  for (int i = 0; i < 8; ++i) {
    o0[i] = (__bf16)(f[i] * invs);
    o1[i] = (__bf16)(f[8 + i] * invs);
  }
  ((bf16x8*)rp)[tid * 2] = o0;
  ((bf16x8*)rp)[tid * 2 + 1] = o1;
}

// ---------------------------------------------------------------------------
// MFMA GEMM, m97 structure + T3-min double-buffer + T1 XCD-chunked swizzle.
// D[m,n] = scale * sum_k A[m,k]*B[n,k] (+bias). 128x128 tile, BK=32, 4 waves.
// One __syncthreads per K-step; STAGE(t+1) issued before compute(t) so the
// global_load_lds of the next tile is in flight across the MFMA phase.
// EPI: 0 = bf16 out, 1 = f32 out, 2 = f32 out * xmul(bf16). BIAS: 0/1(col)/2(row).
// ---------------------------------------------------------------------------
template <int EPI, int BIAS>
__global__ __launch_bounds__(256) void gemm_lds_kernel(
    const __bf16* __restrict__ A, int lda, long long sA,
    const __bf16* __restrict__ Bm, int ldb, long long sB,
    void* __restrict__ Out, int ldo, long long sO,
    const float* __restrict__ bias, const __bf16* __restrict__ xmul,
    long long sX, float scale, int K) {
  __shared__ __bf16 sTa[2][128 * 32];
  __shared__ __bf16 sTb[2][128 * 32];

  // T1: XCD-chunked block swizzle (all grids are multiples of 8)
  const int gx = gridDim.x, gxy = gx * gridDim.y;
  const int nwg = gxy * gridDim.z;
  int bid = blockIdx.x + gx * blockIdx.y + gxy * blockIdx.z;
  if ((nwg & 7) == 0) bid = (bid & 7) * (nwg >> 3) + (bid >> 3);
  const int bz = bid / gxy;
  const int rem = bid - bz * gxy;
  const int by = rem / gx;
  const int bx = rem - by * gx;

  const int tid = threadIdx.x;
  const int lane = tid & 63;
  const int wid = tid >> 6;
  const int wr = wid >> 1, wc = wid & 1;
  const int tm0 = by * 128, tn0 = bx * 128;
  const int lr = lane & 15, lk = (lane >> 4) * 8;

  // staging pointers (tile 0)
  const int ch0 = wid * 2;
  const int srow = lane >> 2;
  const int scol = (lane & 3) * 8;
  const __bf16* gA0 = A + (size_t)bz * sA + (size_t)(tm0 + ch0 * 16 + srow) * lda + scol;
  const __bf16* gB0 = Bm + (size_t)bz * sB + (size_t)(tn0 + ch0 * 16 + srow) * ldb + scol;
  const size_t stepA = (size_t)16 * lda, stepB = (size_t)16 * ldb;

  f32x4 acc[4][4];
#pragma unroll
  for (int i = 0; i < 4; ++i)
#pragma unroll
    for (int j = 0; j < 4; ++j) acc[i][j] = f32x4{0.f, 0.f, 0.f, 0.f};

  const int T = K >> 5;
  // prologue: stage tile 0 into buf 0
  gload_lds16(gA0, &sTa[0][ch0 * 512]);
  gload_lds16(gA0 + stepA, &sTa[0][ch0 * 512 + 512]);
  gload_lds16(gB0, &sTb[0][ch0 * 512]);
  gload_lds16(gB0 + stepB, &sTb[0][ch0 * 512 + 512]);

  for (int t = 0; t < T; ++t) {
    __syncthreads();  // drains vmcnt(0): tile t resident; prev reads complete
    const int cur = t & 1;
    if (t + 1 < T) {
      const __bf16* a = gA0 + (size_t)(t + 1) * 32;
      const __bf16* b = gB0 + (size_t)(t + 1) * 32;
      gload_lds16(a, &sTa[cur ^ 1][ch0 * 512]);
      gload_lds16(a + stepA, &sTa[cur ^ 1][ch0 * 512 + 512]);
      gload_lds16(b, &sTb[cur ^ 1][ch0 * 512]);
      gload_lds16(b + stepB, &sTb[cur ^ 1][ch0 * 512 + 512]);
    }
    const __bf16* fa = &sTa[cur][(wr * 64 + lr) * 32 + lk];
    const __bf16* fb = &sTb[cur][(wc * 64 + lr) * 32 + lk];
    bf16x8 a[4], b[4];
#pragma unroll
    for (int i = 0; i < 4; ++i) a[i] = *(const bf16x8*)(fa + i * 512);
#pragma unroll
    for (int j = 0; j < 4; ++j) b[j] = *(const bf16x8*)(fb + j * 512);
#pragma unroll
    for (int i = 0; i < 4; ++i)
#pragma unroll
      for (int j = 0; j < 4; ++j)
        acc[i][j] = __builtin_amdgcn_mfma_f32_16x16x32_bf16(a[i], b[j], acc[i][j], 0, 0, 0);
  }

  // Epilogue. D mapping (verified m89): col = lane&15, row = (lane>>4)*4 + reg.
  const int wm = tm0 + wr * 64, wn = tn0 + wc * 64;
#pragma unroll
  for (int i = 0; i < 4; ++i) {
#pragma unroll
    for (int r = 0; r < 4; ++r) {
      const int row = wm + i * 16 + (lane >> 4) * 4 + r;
#pragma unroll
      for (int j = 0; j < 4; ++j) {
        const int col = wn + j * 16 + lr;
        float val = acc[i][j][r] * scale;
        if (BIAS == 1) val += bias[col];
        if (BIAS == 2) val += bias[row];
        const size_t off = (size_t)bz * sO + (size_t)row * ldo + col;
        if (EPI == 0) {
          ((__bf16*)Out)[off] = (__bf16)val;
        } else if (EPI == 1) {
          ((float*)Out)[off] = val;
        } else {
          ((float*)Out)[off] = (float)xmul[(size_t)bz * sX + (size_t)row * ldo + col] * val;
        }
      }
    }
  }
}

// ---------------------------------------------------------------------------
// Workspace (batched, ~194 MiB):
//   S4  [4,4096,4096] bf16 @ 0       (128 MiB; hnT [4,4096,512] aliases first 16)
//   qkT [4,4096,1024] bf16 @ 128 MiB (32 MiB; a2T aliases first 16 after QK)
//   v   [4,512,4096]  bf16 @ 160 MiB (16)
//   xbf [4,512,4096]  bf16 @ 176 MiB (16)
//   wB  4x[512,512]   bf16 @ 192 MiB (2)
//   bqk f32[1024] @ 194 MiB; gmbt f32x2[4,512] @ +4K; part f32x2[1024] @ +20K
// Serial fallback (~115 MiB): S 32 @0 (hnT alias), qkT @32, a2T @64, v @80,
//   xbf @96, wB @112, misc @114.
// ---------------------------------------------------------------------------
extern "C" void kernel_launch(void* const* d_in, const int* in_sizes, int n_in,
                              void* d_out, int out_size, void* d_ws, size_t ws_size,
                              hipStream_t stream) {
  const int C = 512, N = 4096;
  const float* x = (const float*)d_in[0];
  const float* gng = (const float*)d_in[1];
  const float* gnb = (const float*)d_in[2];
  const float* wq = (const float*)d_in[3];
  const float* bq = (const float*)d_in[4];
  const float* wk = (const float*)d_in[5];
  const float* bk = (const float*)d_in[6];
  const float* wv = (const float*)d_in[7];
  const float* bv = (const float*)d_in[8];
  const float* wo = (const float*)d_in[9];
  const float* bo = (const float*)d_in[10];

  char* ws = (char*)d_ws;
  const size_t MB = 1ull << 20;
  const long long NC = (long long)N * C;
  const long long NN = (long long)N * N;
  const long long NQK = (long long)N * 1024;
  const bool batched = ws_size >= 194 * MB + 32768;

  __bf16 *S, *qkT, *a2T, *v, *xbf, *wqB;
  char* misc;
  if (batched) {
    S   = (__bf16*)(ws);
    qkT = (__bf16*)(ws + 128 * MB);
    a2T = qkT;  // qkT dead once QK has run
    v   = (__bf16*)(ws + 160 * MB);
    xbf = (__bf16*)(ws + 176 * MB);
    wqB = (__bf16*)(ws + 192 * MB);
    misc = ws + 194 * MB;
  } else {
    S   = (__bf16*)(ws);
    qkT = (__bf16*)(ws + 32 * MB);
    a2T = (__bf16*)(ws + 64 * MB);
    v   = (__bf16*)(ws + 80 * MB);
    xbf = (__bf16*)(ws + 96 * MB);
    wqB = (__bf16*)(ws + 112 * MB);
    misc = ws + 114 * MB;
  }
  __bf16* hnT = (__bf16*)ws;  // aliases S; dead before QK writes S
  __bf16* wkB = wqB + 262144;
  __bf16* wvB = wkB + 262144;
  __bf16* woB = wvB + 262144;
  float* bqk   = (float*)misc;
  float2* gmbt = (float2*)(misc + 4096);
  float2* part = (float2*)(misc + 20480);

  const float scl = 0.044194173824159216f;  // 512^-0.5

  cvt4_kernel<<<4096, 256, 0, stream>>>(wq, wk, wv, wo, wqB);
  biascat_kernel<<<4, 256, 0, stream>>>(bq, bk, bqk);
  gn1a_kernel<<<1024, 256, 0, stream>>>(x, xbf, part);
  gn1b_kernel<<<4, 512, 0, stream>>>(part, gng, gnb, gmbt);
  gn2_kernel<<<dim3(64, 8, 4), 256, 0, stream>>>(xbf, gmbt, hnT);

  // fused q,k projection: qkT[b,n,0:512]=q, [512:1024]=k
  gemm_lds_kernel<0, 1><<<dim3(8, 32, 4), 256, 0, stream>>>(
      hnT, C, NC, wqB, C, 0, qkT, 1024, NQK, bqk, nullptr, 0, 1.f, C);
  // v[b,c,n]
  gemm_lds_kernel<0, 2><<<dim3(32, 4, 4), 256, 0, stream>>>(
      wvB, C, 0, hnT, C, NC, v, N, NC, bv, nullptr, 0, 1.f, C);

  if (batched) {
    gemm_lds_kernel<0, 0><<<dim3(32, 32, 4), 256, 0, stream>>>(
        qkT, 1024, NQK, qkT + 512, 1024, NQK, S, N, NN, nullptr, nullptr, 0, scl, C);
    softmax_bf16_kernel<<<4 * 4096, 256, 0, stream>>>(S);
    gemm_lds_kernel<0, 0><<<dim3(4, 32, 4), 256, 0, stream>>>(
        S, N, NN, v, N, NC, a2T, C, NC, nullptr, nullptr, 0, 1.f, N);
  } else {
    for (int b = 0; b < 4; ++b) {
      gemm_lds_kernel<0, 0><<<dim3(32, 32, 1), 256, 0, stream>>>(
          qkT + (size_t)b * NQK, 1024, 0, qkT + (size_t)b * NQK + 512, 1024, 0,
          S, N, 0, nullptr, nullptr, 0, scl, C);
      softmax_bf16_kernel<<<4096, 256, 0, stream>>>(S);
      gemm_lds_kernel<0, 0><<<dim3(4, 32, 1), 256, 0, stream>>>(
          S, N, 0, v + (size_t)b * NC, N, 0, a2T + (size_t)b * NC, C, 0,
          nullptr, nullptr, 0, 1.f, N);
    }
  }

  // out[b,c,n] = xbf[b,c,n] * (sum_k wo[c,k] * a2T[b,n,k] + bo[c])
  gemm_lds_kernel<2, 2><<<dim3(32, 4, 4), 256, 0, stream>>>(
      woB, C, 0, a2T, C, NC, d_out, N, NC, bo, xbf, NC, 1.f, C);
}

// Round 4
// 292.708 us; speedup vs baseline: 2.9410x; 1.1017x over previous
//
#include <hip/hip_runtime.h>
#include <hip/hip_bf16.h>
#include <stdint.h>

typedef __bf16 bf16x8 __attribute__((ext_vector_type(8)));
typedef __bf16 bf16x4 __attribute__((ext_vector_type(4)));
typedef float f32x4 __attribute__((ext_vector_type(4)));

__device__ __forceinline__ void gload_lds16(const __bf16* g, __bf16* l) {
  __builtin_amdgcn_global_load_lds(
      (const __attribute__((address_space(1))) void*)g,
      (__attribute__((address_space(3))) void*)l, 16, 0, 0);
}

// ---------------------------------------------------------------------------
// fp32 -> bf16 convert for the 4 weight matrices (contiguous dst)
// ---------------------------------------------------------------------------
__global__ __launch_bounds__(256) void cvt4_kernel(const float* __restrict__ s0,
                                                   const float* __restrict__ s1,
                                                   const float* __restrict__ s2,
                                                   const float* __restrict__ s3,
                                                   __bf16* __restrict__ dst) {
  int i = blockIdx.x * 256 + threadIdx.x;
  const float* srcs[4] = {s0, s1, s2, s3};
  int m = i >> 18;
  dst[i] = (__bf16)srcs[m][i & 262143];
}

__global__ __launch_bounds__(256) void biascat_kernel(const float* __restrict__ bq,
                                                      const float* __restrict__ bk,
                                                      float* __restrict__ bqk) {
  int i = blockIdx.x * 256 + threadIdx.x;  // 1024
  bqk[i] = (i < 512) ? bq[i] : bk[i - 512];
}

// ---------------------------------------------------------------------------
// GN1a: stream x fp32 once; write xbf + per-(b,g,slice) partial sums.
// ---------------------------------------------------------------------------
__global__ __launch_bounds__(256) void gn1a_kernel(const float* __restrict__ x,
                                                   __bf16* __restrict__ xbf,
                                                   float2* __restrict__ part) {
  const int tid = threadIdx.x;
  const size_t base4 = ((size_t)blockIdx.x * 8192) >> 2;
  const float4* x4 = (const float4*)x;
  bf16x4* o4 = (bf16x4*)xbf;

  float s1 = 0.f, s2 = 0.f;
#pragma unroll
  for (int j = 0; j < 8; ++j) {
    float4 t = x4[base4 + tid + j * 256];
    s1 += t.x + t.y + t.z + t.w;
    s2 += t.x * t.x + t.y * t.y + t.z * t.z + t.w * t.w;
    bf16x4 o;
    o[0] = (__bf16)t.x; o[1] = (__bf16)t.y; o[2] = (__bf16)t.z; o[3] = (__bf16)t.w;
    o4[base4 + tid + j * 256] = o;
  }
#pragma unroll
  for (int off = 32; off; off >>= 1) {
    s1 += __shfl_xor(s1, off);
    s2 += __shfl_xor(s2, off);
  }
  __shared__ float r1[4], r2[4];
  if ((tid & 63) == 0) { r1[tid >> 6] = s1; r2[tid >> 6] = s2; }
  __syncthreads();
  if (tid == 0)
    part[blockIdx.x] = float2{r1[0] + r1[1] + r1[2] + r1[3],
                              r2[0] + r2[1] + r2[2] + r2[3]};
}

__global__ __launch_bounds__(512) void gn1b_kernel(const float2* __restrict__ part,
                                                   const float* __restrict__ gamma,
                                                   const float* __restrict__ beta,
                                                   float2* __restrict__ gmbt) {
  const int b = blockIdx.x;
  const int t = threadIdx.x;
  __shared__ float sm[32], si[32];
  if (t < 32) {
    float s1 = 0.f, s2 = 0.f;
#pragma unroll
    for (int j = 0; j < 8; ++j) {
      float2 p = part[(b * 32 + t) * 8 + j];
      s1 += p.x; s2 += p.y;
    }
    const float mean = s1 * (1.f / 65536.f);
    const float var = s2 * (1.f / 65536.f) - mean * mean;
    sm[t] = mean;
    si[t] = rsqrtf(var + 1e-6f);
  }
  __syncthreads();
  const int g = t >> 4;
  const float gm = gamma[t] * si[g];
  gmbt[b * 512 + t] = float2{gm, beta[t] - sm[g] * gm};
}

// ---------------------------------------------------------------------------
// GN2: normalize + transpose. xbf [b,c,n] -> hnT [b,n,c] bf16.
// ---------------------------------------------------------------------------
__global__ __launch_bounds__(256) void gn2_kernel(const __bf16* __restrict__ xbf,
                                                  const float2* __restrict__ gmbt,
                                                  __bf16* __restrict__ hnT) {
  const int b = blockIdx.z;
  const int c0 = blockIdx.y * 64;
  const int n0 = blockIdx.x * 64;
  const int t = threadIdx.x;
  __shared__ __bf16 tile[64][72];

  {
    const int row = t >> 2;
    const int col = (t & 3) * 16;
    const __bf16* src = xbf + ((size_t)(b * 512 + c0 + row)) * 4096 + n0 + col;
    bf16x8 u0 = *(const bf16x8*)src;
    bf16x8 u1 = *(const bf16x8*)(src + 8);
    *(bf16x8*)&tile[row][col] = u0;
    *(bf16x8*)&tile[row][col + 8] = u1;
  }
  __syncthreads();
  {
    const int nrow = t >> 2;
    const int cc = (t & 3) * 16;
    bf16x8 o0, o1;
#pragma unroll
    for (int j = 0; j < 16; ++j) {
      const int c = c0 + cc + j;
      float2 s = gmbt[b * 512 + c];
      float val = (float)tile[cc + j][nrow] * s.x + s.y;
      if (j < 8) o0[j] = (__bf16)val; else o1[j - 8] = (__bf16)val;
    }
    __bf16* dst = hnT + ((size_t)b * 4096 + n0 + nrow) * 512 + c0 + cc;
    *(bf16x8*)dst = o0;
    *(bf16x8*)(dst + 8) = o1;
  }
}

// ---------------------------------------------------------------------------
// Row softmax over bf16 rows of length 4096, in place. One block per row.
// ---------------------------------------------------------------------------
__global__ __launch_bounds__(256) void softmax_bf16_kernel(__bf16* __restrict__ S) {
  const int N = 4096;
  __bf16* rp = S + (size_t)blockIdx.x * N;
  const int tid = threadIdx.x;
  bf16x8 v0 = ((const bf16x8*)rp)[tid * 2];
  bf16x8 v1 = ((const bf16x8*)rp)[tid * 2 + 1];
  float f[16];
#pragma unroll
  for (int i = 0; i < 8; ++i) { f[i] = (float)v0[i]; f[8 + i] = (float)v1[i]; }

  float mx = -1e30f;
#pragma unroll
  for (int i = 0; i < 16; ++i) mx = fmaxf(mx, f[i]);
#pragma unroll
  for (int off = 32; off; off >>= 1) mx = fmaxf(mx, __shfl_xor(mx, off));
  __shared__ float redm[4];
  if ((tid & 63) == 0) redm[tid >> 6] = mx;
  __syncthreads();
  mx = fmaxf(fmaxf(redm[0], redm[1]), fmaxf(redm[2], redm[3]));

  float sum = 0.f;
#pragma unroll
  for (int i = 0; i < 16; ++i) {
    f[i] = __expf(f[i] - mx);
    sum += f[i];
  }
#pragma unroll
  for (int off = 32; off; off >>= 1) sum += __shfl_xor(sum, off);
  __shared__ float reds[4];
  if ((tid & 63) == 0) reds[tid >> 6] = sum;
  __syncthreads();
  sum = reds[0] + reds[1] + reds[2] + reds[3];
  const float invs = 1.0f / sum;

  bf16x8 o0, o1;
#pragma unroll
  for (int i = 0; i < 8; ++i) {
    o0[i] = (__bf16)(f[i] * invs);
    o1[i] = (__bf16)(f[8 + i] * invs);
  }
  ((bf16x8*)rp)[tid * 2] = o0;
  ((bf16x8*)rp)[tid * 2 + 1] = o1;
}

// ---------------------------------------------------------------------------
// 8-phase 8-wave MFMA GEMM engine (T1+T2+T3+T4+T5).
// D[m,n] = scale * sum_k A[m,k]*B[n,k] (+ bias[col]); bf16 in/out, f32 acc.
// BM=256, BK=64 as 2 k-slots of 32; ring of 4 LDS slots per operand.
// 8 waves 2x4: per-wave 128 x BN/4. Requires M%256==0, N%BN==0, K%64==0, K>=256.
// LDS slots [256][32] (A) / [BN][32] (B), XOR-swizzled: byte ^= ((row>>1)&3)<<4,
// realized as pre-swizzled global staging source + swizzled ds_read (rule #21).
// vmcnt: uniform (8) [BN=256] / (6) [BN=128] on even phases; last iter peeled.
// ---------------------------------------------------------------------------
template <int BN, int BIAS>
__global__ __launch_bounds__(512) void gemm8p_kernel(
    const __bf16* __restrict__ A, int lda, long long sA,
    const __bf16* __restrict__ Bm, int ldb, long long sB,
    __bf16* __restrict__ Out, int ldo, long long sO,
    const float* __restrict__ bias, float scale, int K) {
  constexpr int NF = BN / 64;   // n-frags per wave (4 or 2)
  constexpr int NH = NF / 2;    // n-frags per phase (2 or 1)
  constexpr int BSLOT = BN * 32;
  __shared__ __bf16 sm[4 * 8192 + 4 * BSLOT];
  __bf16* smB = sm + 4 * 8192;

  // T1: XCD-chunked swizzle (all grids used are multiples of 8)
  const int gx = gridDim.x, gxy = gx * gridDim.y;
  const int nwg = gxy * gridDim.z;
  int bid = blockIdx.x + gx * blockIdx.y + gxy * blockIdx.z;
  bid = (bid & 7) * (nwg >> 3) + (bid >> 3);
  const int bz = bid / gxy;
  const int rem = bid - bz * gxy;
  const int by = rem / gx, bx = rem - by * gx;
  const int tm0 = by * 256, tn0 = bx * BN;

  const int t = threadIdx.x;
  const int lane = t & 63, wid = t >> 6;
  const int wr = wid >> 2, wc = wid & 3;

  const __bf16* Az = A + (size_t)bz * sA;
  const __bf16* Bz = Bm + (size_t)bz * sB;

  // staging sources (pre-swizzled col so linear LDS + swizzled read = identity)
  const int scol = ((t & 3) * 8) ^ (((t >> 3) & 3) * 8);
  const __bf16* gA0 = Az + (size_t)(tm0 + (t >> 2)) * lda + scol;
  const __bf16* gA1 = gA0 + (size_t)128 * lda;
  const __bf16* gB0 = Bz + (size_t)(tn0 + (t >> 2)) * ldb + scol;
  const __bf16* gB1 = gB0 + (size_t)128 * ldb;  // unused when BN==128
  __bf16* dA = sm + t * 8;
  __bf16* dB = smB + t * 8;

  auto stageA = [&](int ko, int sl) {
    gload_lds16(gA0 + ko, dA + sl * 8192);
    gload_lds16(gA1 + ko, dA + sl * 8192 + 4096);
  };
  auto stageB = [&](int ko, int sl) {
    gload_lds16(gB0 + ko, dB + sl * BSLOT);
    if constexpr (BN == 256) gload_lds16(gB1 + ko, dB + sl * BSLOT + 4096);
  };
  auto vmw = [&] {
    if constexpr (BN == 256) asm volatile("s_waitcnt vmcnt(8)" ::: "memory");
    else                     asm volatile("s_waitcnt vmcnt(6)" ::: "memory");
  };

  // swizzled fragment read bases
  const int lr = lane & 15;
  const int kb = ((lane >> 4) * 16) ^ ((lr & 6) << 3);  // byte off within row
  const __bf16* rdA = sm + (((wr * 128 + lr) * 64 + kb) >> 1);
  const __bf16* rdB = smB + (((wc * (BN / 4) + lr) * 64 + kb) >> 1);

  f32x4 acc[8][NF];
#pragma unroll
  for (int m = 0; m < 8; ++m)
#pragma unroll
    for (int n = 0; n < NF; ++n) acc[m][n] = f32x4{0.f, 0.f, 0.f, 0.f};
  bf16x8 av[8];

  auto rdAfr = [&](int sl) {
#pragma unroll
    for (int m = 0; m < 8; ++m)
      av[m] = *(const bf16x8*)(rdA + sl * 8192 + m * 512);
  };
  auto mmaPh = [&](int sl, int nh) {
    bf16x8 bv[NH];
#pragma unroll
    for (int j = 0; j < NH; ++j)
      bv[j] = *(const bf16x8*)(rdB + sl * BSLOT + (nh * NH + j) * 512);
    __builtin_amdgcn_s_barrier();
    __builtin_amdgcn_s_setprio(1);
#pragma unroll
    for (int m = 0; m < 8; ++m)
#pragma unroll
      for (int j = 0; j < NH; ++j)
        acc[m][nh * NH + j] = __builtin_amdgcn_mfma_f32_16x16x32_bf16(
            av[m], bv[j], acc[m][nh * NH + j], 0, 0, 0);
    __builtin_amdgcn_s_setprio(0);
    __builtin_amdgcn_s_barrier();
  };

  const int NT = K >> 6;        // BK=64 tiles (even, >=4)
  const int NIT = NT >> 1;

  // prologue: stage tiles 0,1 (units in consumption order), drain first pair
  stageA(0, 0); stageB(0, 0); stageA(32, 1); stageB(32, 1);
  stageA(64, 2); stageB(64, 2);
  vmw();
  __builtin_amdgcn_s_barrier();

  for (int it = 0; it < NIT - 1; ++it) {
    const int kt = it * 2;
    const int k0 = kt * 64;
    // ph1..ph8: slots 0,1,2,3 = (kt,ks0),(kt,ks1),(kt+1,ks0),(kt+1,ks1)
    rdAfr(0); stageA(k0 + 96, 3);          mmaPh(0, 0);
    stageB(k0 + 96, 3); vmw();             mmaPh(0, 1);
    rdAfr(1); stageA(k0 + 128, 0);         mmaPh(1, 0);
    stageB(k0 + 128, 0); vmw();            mmaPh(1, 1);
    rdAfr(2); stageA(k0 + 160, 1);         mmaPh(2, 0);
    stageB(k0 + 160, 1); vmw();            mmaPh(2, 1);
    rdAfr(3); stageA(k0 + 192, 2);         mmaPh(3, 0);
    stageB(k0 + 192, 2); vmw();            mmaPh(3, 1);
  }
  {  // peeled last iter: only (kt+1,ks1) still needs staging; strict waits
    const int k0 = (NT - 2) * 64;
    rdAfr(0); stageA(k0 + 96, 3);          mmaPh(0, 0);
    stageB(k0 + 96, 3); vmw();             mmaPh(0, 1);
    rdAfr(1);                              mmaPh(1, 0);
    if constexpr (BN == 256) asm volatile("s_waitcnt vmcnt(4)" ::: "memory");
    else                     asm volatile("s_waitcnt vmcnt(3)" ::: "memory");
    mmaPh(1, 1);
    rdAfr(2);                              mmaPh(2, 0);
    if constexpr (BN == 256) asm volatile("s_waitcnt vmcnt(2)" ::: "memory");
    else                     asm volatile("s_waitcnt vmcnt(1)" ::: "memory");
    mmaPh(2, 1);
    rdAfr(3);                              mmaPh(3, 0);
    mmaPh(3, 1);
  }

  // epilogue: D mapping col=lane&15, row=(lane>>4)*4+reg (verified m89)
  const int q4 = (lane >> 4) * 4;
  const int wnb = tn0 + wc * (BN / 4);
  float bcol[NF];
#pragma unroll
  for (int n = 0; n < NF; ++n) bcol[n] = BIAS ? bias[wnb + n * 16 + lr] : 0.f;
#pragma unroll
  for (int m = 0; m < 8; ++m) {
#pragma unroll
    for (int r = 0; r < 4; ++r) {
      const int row = tm0 + wr * 128 + m * 16 + q4 + r;
      __bf16* orow = Out + (size_t)bz * sO + (size_t)row * ldo + wnb + lr;
#pragma unroll
      for (int n = 0; n < NF; ++n)
        orow[n * 16] = (__bf16)(acc[m][n][r] * scale + bcol[n]);
    }
  }
}

// ---------------------------------------------------------------------------
// 2-phase 128x128 GEMM (kept for skinny shapes: v-proj, out-proj).
// EPI: 0 = bf16 out, 1 = f32 out, 2 = f32 out * xmul(bf16). BIAS: 0/1(col)/2(row).
// ---------------------------------------------------------------------------
template <int EPI, int BIAS>
__global__ __launch_bounds__(256) void gemm_lds_kernel(
    const __bf16* __restrict__ A, int lda, long long sA,
    const __bf16* __restrict__ Bm, int ldb, long long sB,
    void* __restrict__ Out, int ldo, long long sO,
    const float* __restrict__ bias, const __bf16* __restrict__ xmul,
    long long sX, float scale, int K) {
  __shared__ __bf16 sTa[2][128 * 32];
  __shared__ __bf16 sTb[2][128 * 32];

  const int gx = gridDim.x, gxy = gx * gridDim.y;
  const int nwg = gxy * gridDim.z;
  int bid = blockIdx.x + gx * blockIdx.y + gxy * blockIdx.z;
  if ((nwg & 7) == 0) bid = (bid & 7) * (nwg >> 3) + (bid >> 3);
  const int bz = bid / gxy;
  const int rem = bid - bz * gxy;
  const int by = rem / gx;
  const int bx = rem - by * gx;

  const int tid = threadIdx.x;
  const int lane = tid & 63;
  const int wid = tid >> 6;
  const int wr = wid >> 1, wc = wid & 1;
  const int tm0 = by * 128, tn0 = bx * 128;
  const int lr = lane & 15, lk = (lane >> 4) * 8;

  const int ch0 = wid * 2;
  const int srow = lane >> 2;
  const int scol = (lane & 3) * 8;
  const __bf16* gA0 = A + (size_t)bz * sA + (size_t)(tm0 + ch0 * 16 + srow) * lda + scol;
  const __bf16* gB0 = Bm + (size_t)bz * sB + (size_t)(tn0 + ch0 * 16 + srow) * ldb + scol;
  const size_t stepA = (size_t)16 * lda, stepB = (size_t)16 * ldb;

  f32x4 acc[4][4];
#pragma unroll
  for (int i = 0; i < 4; ++i)
#pragma unroll
    for (int j = 0; j < 4; ++j) acc[i][j] = f32x4{0.f, 0.f, 0.f, 0.f};

  const int T = K >> 5;
  gload_lds16(gA0, &sTa[0][ch0 * 512]);
  gload_lds16(gA0 + stepA, &sTa[0][ch0 * 512 + 512]);
  gload_lds16(gB0, &sTb[0][ch0 * 512]);
  gload_lds16(gB0 + stepB, &sTb[0][ch0 * 512 + 512]);

  for (int tt = 0; tt < T; ++tt) {
    __syncthreads();
    const int cur = tt & 1;
    if (tt + 1 < T) {
      const __bf16* a = gA0 + (size_t)(tt + 1) * 32;
      const __bf16* b = gB0 + (size_t)(tt + 1) * 32;
      gload_lds16(a, &sTa[cur ^ 1][ch0 * 512]);
      gload_lds16(a + stepA, &sTa[cur ^ 1][ch0 * 512 + 512]);
      gload_lds16(b, &sTb[cur ^ 1][ch0 * 512]);
      gload_lds16(b + stepB, &sTb[cur ^ 1][ch0 * 512 + 512]);
    }
    const __bf16* fa = &sTa[cur][(wr * 64 + lr) * 32 + lk];
    const __bf16* fb = &sTb[cur][(wc * 64 + lr) * 32 + lk];
    bf16x8 a[4], b[4];
#pragma unroll
    for (int i = 0; i < 4; ++i) a[i] = *(const bf16x8*)(fa + i * 512);
#pragma unroll
    for (int j = 0; j < 4; ++j) b[j] = *(const bf16x8*)(fb + j * 512);
#pragma unroll
    for (int i = 0; i < 4; ++i)
#pragma unroll
      for (int j = 0; j < 4; ++j)
        acc[i][j] = __builtin_amdgcn_mfma_f32_16x16x32_bf16(a[i], b[j], acc[i][j], 0, 0, 0);
  }

  const int wm = tm0 + wr * 64, wn = tn0 + wc * 64;
#pragma unroll
  for (int i = 0; i < 4; ++i) {
#pragma unroll
    for (int r = 0; r < 4; ++r) {
      const int row = wm + i * 16 + (lane >> 4) * 4 + r;
#pragma unroll
      for (int j = 0; j < 4; ++j) {
        const int col = wn + j * 16 + lr;
        float val = acc[i][j][r] * scale;
        if (BIAS == 1) val += bias[col];
        if (BIAS == 2) val += bias[row];
        const size_t off = (size_t)bz * sO + (size_t)row * ldo + col;
        if (EPI == 0) {
          ((__bf16*)Out)[off] = (__bf16)val;
        } else if (EPI == 1) {
          ((float*)Out)[off] = val;
        } else {
          ((float*)Out)[off] = (float)xmul[(size_t)bz * sX + (size_t)row * ldo + col] * val;
        }
      }
    }
  }
}

// ---------------------------------------------------------------------------
// Workspace layout: identical to round 3 (batched ~194 MiB / serial ~115 MiB).
// ---------------------------------------------------------------------------
extern "C" void kernel_launch(void* const* d_in, const int* in_sizes, int n_in,
                              void* d_out, int out_size, void* d_ws, size_t ws_size,
                              hipStream_t stream) {
  const int C = 512, N = 4096;
  const float* x = (const float*)d_in[0];
  const float* gng = (const float*)d_in[1];
  const float* gnb = (const float*)d_in[2];
  const float* wq = (const float*)d_in[3];
  const float* bq = (const float*)d_in[4];
  const float* wk = (const float*)d_in[5];
  const float* bk = (const float*)d_in[6];
  const float* wv = (const float*)d_in[7];
  const float* bv = (const float*)d_in[8];
  const float* wo = (const float*)d_in[9];
  const float* bo = (const float*)d_in[10];

  char* ws = (char*)d_ws;
  const size_t MB = 1ull << 20;
  const long long NC = (long long)N * C;
  const long long NN = (long long)N * N;
  const long long NQK = (long long)N * 1024;
  const bool batched = ws_size >= 194 * MB + 32768;

  __bf16 *S, *qkT, *a2T, *v, *xbf, *wqB;
  char* misc;
  if (batched) {
    S   = (__bf16*)(ws);
    qkT = (__bf16*)(ws + 128 * MB);
    a2T = qkT;
    v   = (__bf16*)(ws + 160 * MB);
    xbf = (__bf16*)(ws + 176 * MB);
    wqB = (__bf16*)(ws + 192 * MB);
    misc = ws + 194 * MB;
  } else {
    S   = (__bf16*)(ws);
    qkT = (__bf16*)(ws + 32 * MB);
    a2T = (__bf16*)(ws + 64 * MB);
    v   = (__bf16*)(ws + 80 * MB);
    xbf = (__bf16*)(ws + 96 * MB);
    wqB = (__bf16*)(ws + 112 * MB);
    misc = ws + 114 * MB;
  }
  __bf16* hnT = (__bf16*)ws;  // aliases S; dead before QK writes S
  __bf16* wvB = wqB + 2 * 262144;
  __bf16* woB = wvB + 262144;
  float* bqk   = (float*)misc;
  float2* gmbt = (float2*)(misc + 4096);
  float2* part = (float2*)(misc + 20480);

  const float scl = 0.044194173824159216f;  // 512^-0.5

  cvt4_kernel<<<4096, 256, 0, stream>>>(wq, wk, wv, wo, wqB);
  biascat_kernel<<<4, 256, 0, stream>>>(bq, bk, bqk);
  gn1a_kernel<<<1024, 256, 0, stream>>>(x, xbf, part);
  gn1b_kernel<<<4, 512, 0, stream>>>(part, gng, gnb, gmbt);
  gn2_kernel<<<dim3(64, 8, 4), 256, 0, stream>>>(xbf, gmbt, hnT);

  // fused q,k projection: qkT[b,n,0:512]=q, [512:1024]=k  (engine, BN=256)
  gemm8p_kernel<256, 1><<<dim3(4, 16, 4), 512, 0, stream>>>(
      hnT, C, NC, wqB, C, 0, qkT, 1024, NQK, bqk, 1.f, C);
  // v[b,c,n] (2-phase kernel: M=512 shape)
  gemm_lds_kernel<0, 2><<<dim3(32, 4, 4), 256, 0, stream>>>(
      wvB, C, 0, hnT, C, NC, v, N, NC, bv, nullptr, 0, 1.f, C);

  if (batched) {
    gemm8p_kernel<256, 0><<<dim3(16, 16, 4), 512, 0, stream>>>(
        qkT, 1024, NQK, qkT + 512, 1024, NQK, S, N, NN, nullptr, scl, C);
    softmax_bf16_kernel<<<4 * 4096, 256, 0, stream>>>(S);
    gemm8p_kernel<128, 0><<<dim3(4, 16, 4), 512, 0, stream>>>(
        S, N, NN, v, N, NC, a2T, C, NC, nullptr, 1.f, N);
  } else {
    for (int b = 0; b < 4; ++b) {
      gemm8p_kernel<256, 0><<<dim3(16, 16, 1), 512, 0, stream>>>(
          qkT + (size_t)b * NQK, 1024, 0, qkT + (size_t)b * NQK + 512, 1024, 0,
          S, N, 0, nullptr, scl, C);
      softmax_bf16_kernel<<<4096, 256, 0, stream>>>(S);
      gemm8p_kernel<128, 0><<<dim3(4, 16, 1), 512, 0, stream>>>(
          S, N, 0, v + (size_t)b * NC, N, 0, a2T + (size_t)b * NC, C, 0,
          nullptr, 1.f, N);
    }
  }

  // out[b,c,n] = xbf[b,c,n] * (sum_k wo[c,k] * a2T[b,n,k] + bo[c])
  gemm_lds_kernel<2, 2><<<dim3(32, 4, 4), 256, 0, stream>>>(
      woB, C, 0, a2T, C, NC, (float*)d_out, N, NC, bo, xbf, NC, 1.f, C);
}